// Round 4
// baseline (1888.095 us; speedup 1.0000x reference)
//
#include <hip/hip_runtime.h>
#include <math.h>

#define DD 64      // per-head channels
#define HH 8       // heads
#define HD 512     // HH*DD

// ---------------------------------------------------------------------------
// fp32 tiled GEMM: C[M,N] = A[M,K] @ B[K,N], row-major, N%64==0, K%16==0.
// 64x64 tile, 256 threads, 4x4 register micro-tile.
// ---------------------------------------------------------------------------
__global__ __launch_bounds__(256) void sgemm64(const float* __restrict__ A,
                                               const float* __restrict__ B,
                                               float* __restrict__ C,
                                               int M, int N, int K)
{
    __shared__ float As[16][64];   // [k][m] (A tile transposed)
    __shared__ float Bs[16][64];   // [k][n]

    const int tid = threadIdx.x;
    const int bm  = blockIdx.y * 64;
    const int bn  = blockIdx.x * 64;
    const int tx  = tid & 15;      // n-group
    const int ty  = tid >> 4;      // m-group
    const int arow = tid >> 2;         // 0..63
    const int acol = (tid & 3) << 2;   // 0,4,8,12
    const int brow = tid >> 4;         // 0..15
    const int bcol = (tid & 15) << 2;  // 0..60

    float acc[4][4] = {};

    for (int k0 = 0; k0 < K; k0 += 16) {
        float4 av = make_float4(0.f, 0.f, 0.f, 0.f);
        if (bm + arow < M)
            av = *reinterpret_cast<const float4*>(&A[(size_t)(bm + arow) * K + k0 + acol]);
        As[acol + 0][arow] = av.x;
        As[acol + 1][arow] = av.y;
        As[acol + 2][arow] = av.z;
        As[acol + 3][arow] = av.w;

        *reinterpret_cast<float4*>(&Bs[brow][bcol]) =
            *reinterpret_cast<const float4*>(&B[(size_t)(k0 + brow) * N + bn + bcol]);

        __syncthreads();

        #pragma unroll
        for (int k = 0; k < 16; ++k) {
            const float4 a = *reinterpret_cast<const float4*>(&As[k][ty << 2]);
            const float4 b = *reinterpret_cast<const float4*>(&Bs[k][tx << 2]);
            const float av4[4] = {a.x, a.y, a.z, a.w};
            const float bv4[4] = {b.x, b.y, b.z, b.w};
            #pragma unroll
            for (int i = 0; i < 4; ++i)
                #pragma unroll
                for (int j = 0; j < 4; ++j)
                    acc[i][j] = fmaf(av4[i], bv4[j], acc[i][j]);
        }
        __syncthreads();
    }

    #pragma unroll
    for (int i = 0; i < 4; ++i) {
        const int row = bm + (ty << 2) + i;
        if (row < M)
            *reinterpret_cast<float4*>(&C[(size_t)row * N + bn + (tx << 2)]) =
                make_float4(acc[i][0], acc[i][1], acc[i][2], acc[i][3]);
    }
}

// ---------------------------------------------------------------------------
// Edge pass A: one wave per edge. lane = channel c; 8 heads in registers.
// logit[h] = sum_c leaky_relu(xl[src,h,c] + xr[dst,h,c], 0.2) * att[h,c]
// p = exp(logit)  (softmax is shift-invariant; logits are O(1), no max needed)
// denom[dst,h] += p  (atomic)
// Edges w >= E are virtual self-loops: src = dst = w - E.
// ---------------------------------------------------------------------------
__global__ __launch_bounds__(256) void edge_logits(
    const float* __restrict__ xl, const float* __restrict__ xr,
    const float* __restrict__ att, const int* __restrict__ srcs,
    const int* __restrict__ dsts, int E, int ET,
    float* __restrict__ p, float* __restrict__ denom)
{
    const int w    = (blockIdx.x * blockDim.x + threadIdx.x) >> 6;
    const int lane = threadIdx.x & 63;
    if (w >= ET) return;

    int s, d;
    if (w < E) { s = srcs[w]; d = dsts[w]; }
    else       { s = w - E;   d = s; }

    const float* xls = xl + (size_t)s * HD;
    const float* xrd = xr + (size_t)d * HD;

    float lg[HH];
    #pragma unroll
    for (int h = 0; h < HH; ++h) {
        const float a = xls[h * 64 + lane];
        const float b = xrd[h * 64 + lane];
        float v = a + b;
        v = v > 0.f ? v : 0.2f * v;
        lg[h] = v * att[h * 64 + lane];
    }

    #pragma unroll
    for (int m = 1; m < 64; m <<= 1) {
        #pragma unroll
        for (int h = 0; h < HH; ++h)
            lg[h] += __shfl_xor(lg[h], m, 64);
    }

    if (lane == 0) {
        #pragma unroll
        for (int h = 0; h < HH; ++h) {
            const float pv = __expf(lg[h]);
            p[(size_t)w * HH + h] = pv;
            atomicAdd(&denom[(size_t)d * HH + h], pv);
        }
    }
}

// ---------------------------------------------------------------------------
// Edge pass B: alpha[h] = p[w,h] / denom[dst,h];
// agg[dst, h, c] += xl[src, h, c] * alpha[h]   (fp32 atomics)
// ---------------------------------------------------------------------------
__global__ __launch_bounds__(256) void edge_aggregate(
    const float* __restrict__ xl, const float* __restrict__ p,
    const float* __restrict__ denom, const int* __restrict__ srcs,
    const int* __restrict__ dsts, int E, int ET,
    float* __restrict__ agg)
{
    const int w    = (blockIdx.x * blockDim.x + threadIdx.x) >> 6;
    const int lane = threadIdx.x & 63;
    if (w >= ET) return;

    int s, d;
    if (w < E) { s = srcs[w]; d = dsts[w]; }
    else       { s = w - E;   d = s; }

    const float* xls  = xl  + (size_t)s * HD;
    float*       aggd = agg + (size_t)d * HD;

    #pragma unroll
    for (int h = 0; h < HH; ++h) {
        const float alpha = p[(size_t)w * HH + h] / denom[(size_t)d * HH + h];
        atomicAdd(&aggd[h * 64 + lane], xls[h * 64 + lane] * alpha);
    }
}

// ---------------------------------------------------------------------------
// h1 = elu(agg + b1)   (layer-1 epilogue; concat order == [h][c] memory order)
// ---------------------------------------------------------------------------
__global__ __launch_bounds__(256) void bias_elu(
    const float* __restrict__ agg, const float* __restrict__ b,
    float* __restrict__ out, int total)
{
    const int i = blockIdx.x * blockDim.x + threadIdx.x;
    if (i >= total) return;
    const float v = agg[i] + b[i & (HD - 1)];
    out[i] = v > 0.f ? v : expm1f(v);
}

// ---------------------------------------------------------------------------
// out[n,c] = mean_h(agg[n,h,c]) + b2[c]   (layer-2 epilogue)
// ---------------------------------------------------------------------------
__global__ __launch_bounds__(256) void mean_bias(
    const float* __restrict__ agg, const float* __restrict__ b2,
    float* __restrict__ out, int total)
{
    const int i = blockIdx.x * blockDim.x + threadIdx.x;
    if (i >= total) return;
    const int n = i >> 6, c = i & 63;
    const float* a = agg + (size_t)n * HD + c;
    float sum = 0.f;
    #pragma unroll
    for (int h = 0; h < HH; ++h) sum += a[h * 64];
    out[i] = sum * 0.125f + b2[c];
}

// ---------------------------------------------------------------------------
extern "C" void kernel_launch(void* const* d_in, const int* in_sizes, int n_in,
                              void* d_out, int out_size, void* d_ws, size_t ws_size,
                              hipStream_t stream)
{
    const float* x    = (const float*)d_in[0];
    const int*   ei   = (const int*)  d_in[1];
    const float* Wl1  = (const float*)d_in[2];
    const float* Wr1  = (const float*)d_in[3];
    const float* att1 = (const float*)d_in[4];
    const float* b1   = (const float*)d_in[5];
    const float* Wl2  = (const float*)d_in[6];
    const float* Wr2  = (const float*)d_in[7];
    const float* att2 = (const float*)d_in[8];
    const float* b2   = (const float*)d_in[9];

    const int N  = in_sizes[0] / DD;   // 20000
    const int E  = in_sizes[1] / 2;    // 320000
    const int ET = E + N;              // edges + self-loops

    const int* srcs = ei;
    const int* dsts = ei + E;

    // workspace layout (floats): 4*N*HD + ET*HH + N*HH  (~176 MB)
    float* ws    = (float*)d_ws;
    float* xl    = ws;                         // N*HD
    float* xr    = xl   + (size_t)N * HD;      // N*HD
    float* agg   = xr   + (size_t)N * HD;      // N*HD
    float* h1    = agg  + (size_t)N * HD;      // N*HD
    float* pbuf  = h1   + (size_t)N * HD;      // ET*HH
    float* denom = pbuf + (size_t)ET * HH;     // N*HH

    const dim3 gblk(256);
    const dim3 g1((HD + 63) / 64, (N + 63) / 64);
    const int  eblocks = (ET + 3) / 4;         // 4 waves (=4 edges) per block
    const int  tot = N * HD;

    // ---- layer 1: GATv2Conv(64 -> 64, heads=8, concat) + ELU ----
    sgemm64<<<g1, gblk, 0, stream>>>(x, Wl1, xl, N, HD, DD);
    sgemm64<<<g1, gblk, 0, stream>>>(x, Wr1, xr, N, HD, DD);
    hipMemsetAsync(denom, 0, (size_t)N * HH * sizeof(float), stream);
    edge_logits<<<eblocks, 256, 0, stream>>>(xl, xr, att1, srcs, dsts, E, ET, pbuf, denom);
    hipMemsetAsync(agg, 0, (size_t)N * HD * sizeof(float), stream);
    edge_aggregate<<<eblocks, 256, 0, stream>>>(xl, pbuf, denom, srcs, dsts, E, ET, agg);
    bias_elu<<<(tot + 255) / 256, 256, 0, stream>>>(agg, b1, h1, tot);

    // ---- layer 2: GATv2Conv(512 -> 64, heads=8, mean) ----
    sgemm64<<<g1, gblk, 0, stream>>>(h1, Wl2, xl, N, HD, HD);
    sgemm64<<<g1, gblk, 0, stream>>>(h1, Wr2, xr, N, HD, HD);
    hipMemsetAsync(denom, 0, (size_t)N * HH * sizeof(float), stream);
    edge_logits<<<eblocks, 256, 0, stream>>>(xl, xr, att2, srcs, dsts, E, ET, pbuf, denom);
    hipMemsetAsync(agg, 0, (size_t)N * HD * sizeof(float), stream);
    edge_aggregate<<<eblocks, 256, 0, stream>>>(xl, pbuf, denom, srcs, dsts, E, ET, agg);
    mean_bias<<<(N * DD + 255) / 256, 256, 0, stream>>>(agg, b2, (float*)d_out, N * DD);
}

// Round 6
// 692.029 us; speedup vs baseline: 2.7283x; 2.7283x over previous
//
#include <hip/hip_runtime.h>
#include <math.h>

#define DD 64      // per-head channels
#define HH 8       // heads
#define HD 512     // HH*DD

// ---------------------------------------------------------------------------
// fp32 tiled GEMM: C[M,N] = A[M,K] @ B[K,N], row-major, N%64==0, K%16==0.
// 64x64 tile, 256 threads, 4x4 register micro-tile.
// ---------------------------------------------------------------------------
__global__ __launch_bounds__(256) void sgemm64(const float* __restrict__ A,
                                               const float* __restrict__ B,
                                               float* __restrict__ C,
                                               int M, int N, int K)
{
    __shared__ float As[16][64];   // [k][m] (A tile transposed)
    __shared__ float Bs[16][64];   // [k][n]

    const int tid = threadIdx.x;
    const int bm  = blockIdx.y * 64;
    const int bn  = blockIdx.x * 64;
    const int tx  = tid & 15;      // n-group
    const int ty  = tid >> 4;      // m-group
    const int arow = tid >> 2;         // 0..63
    const int acol = (tid & 3) << 2;   // 0,4,8,12
    const int brow = tid >> 4;         // 0..15
    const int bcol = (tid & 15) << 2;  // 0..60

    float acc[4][4] = {};

    for (int k0 = 0; k0 < K; k0 += 16) {
        float4 av = make_float4(0.f, 0.f, 0.f, 0.f);
        if (bm + arow < M)
            av = *reinterpret_cast<const float4*>(&A[(size_t)(bm + arow) * K + k0 + acol]);
        As[acol + 0][arow] = av.x;
        As[acol + 1][arow] = av.y;
        As[acol + 2][arow] = av.z;
        As[acol + 3][arow] = av.w;

        *reinterpret_cast<float4*>(&Bs[brow][bcol]) =
            *reinterpret_cast<const float4*>(&B[(size_t)(k0 + brow) * N + bn + bcol]);

        __syncthreads();

        #pragma unroll
        for (int k = 0; k < 16; ++k) {
            const float4 a = *reinterpret_cast<const float4*>(&As[k][ty << 2]);
            const float4 b = *reinterpret_cast<const float4*>(&Bs[k][tx << 2]);
            const float av4[4] = {a.x, a.y, a.z, a.w};
            const float bv4[4] = {b.x, b.y, b.z, b.w};
            #pragma unroll
            for (int i = 0; i < 4; ++i)
                #pragma unroll
                for (int j = 0; j < 4; ++j)
                    acc[i][j] = fmaf(av4[i], bv4[j], acc[i][j]);
        }
        __syncthreads();
    }

    #pragma unroll
    for (int i = 0; i < 4; ++i) {
        const int row = bm + (ty << 2) + i;
        if (row < M)
            *reinterpret_cast<float4*>(&C[(size_t)row * N + bn + (tx << 2)]) =
                make_float4(acc[i][0], acc[i][1], acc[i][2], acc[i][3]);
    }
}

// ---------------------------------------------------------------------------
// CSR build (per launch; edge list identical for both layers).
// ---------------------------------------------------------------------------
__global__ __launch_bounds__(256) void hist_deg(const int* __restrict__ dsts,
                                                int E, int ET, int* __restrict__ deg)
{
    const int w = blockIdx.x * blockDim.x + threadIdx.x;
    if (w >= ET) return;
    const int d = (w < E) ? dsts[w] : (w - E);   // w >= E: virtual self-loop
    atomicAdd(&deg[d], 1);
}

// single-block exclusive scan: rowptr[0..n], cursor[0..n-1] = rowptr copy
__global__ __launch_bounds__(256) void scan_rowptr(const int* __restrict__ deg,
                                                   int* __restrict__ rowptr,
                                                   int* __restrict__ cursor, int n)
{
    __shared__ int sums[256];
    const int tid   = threadIdx.x;
    const int chunk = (n + 255) / 256;
    const int lo = min(tid * chunk, n), hi = min(lo + chunk, n);

    int s = 0;
    for (int i = lo; i < hi; ++i) s += deg[i];
    sums[tid] = s;
    __syncthreads();

    // Hillis-Steele inclusive scan over the 256 partial sums
    for (int off = 1; off < 256; off <<= 1) {
        const int t = (tid >= off) ? sums[tid - off] : 0;
        __syncthreads();
        sums[tid] += t;
        __syncthreads();
    }

    int run = sums[tid] - s;   // exclusive prefix of this chunk
    for (int i = lo; i < hi; ++i) {
        rowptr[i] = run;
        cursor[i] = run;
        run += deg[i];
    }
    if (tid == 255) rowptr[n] = run;   // == ET
}

__global__ __launch_bounds__(256) void scatter_csr(const int* __restrict__ srcs,
                                                   const int* __restrict__ dsts,
                                                   int E, int ET,
                                                   int* __restrict__ cursor,
                                                   int* __restrict__ eidx)
{
    const int w = blockIdx.x * blockDim.x + threadIdx.x;
    if (w >= ET) return;
    int s, d;
    if (w < E) { s = srcs[w]; d = dsts[w]; }
    else       { s = w - E;   d = s; }
    const int pos = atomicAdd(&cursor[d], 1);
    eidx[pos] = s;
}

// ---------------------------------------------------------------------------
// Fused GATv2 edge pipeline, one wave per dst node, CSR gather, no atomics.
// out[d] = (sum_e p_e * xl[s_e]) / (sum_e p_e),  p_e = exp(logit_e)
// lane layout: lane covers channels [c4..c4+3] of heads h0=lane>>4 and h0+4.
// Softmax shift-invariance: logits are O(1) here, so no max subtraction.
// ---------------------------------------------------------------------------
__device__ __forceinline__ float lrdot4(const float4 v, const float4 r, const float4 a)
{
    float t, s = 0.f;
    t = v.x + r.x; t = t > 0.f ? t : 0.2f * t; s = fmaf(t, a.x, s);
    t = v.y + r.y; t = t > 0.f ? t : 0.2f * t; s = fmaf(t, a.y, s);
    t = v.z + r.z; t = t > 0.f ? t : 0.2f * t; s = fmaf(t, a.z, s);
    t = v.w + r.w; t = t > 0.f ? t : 0.2f * t; s = fmaf(t, a.w, s);
    return s;
}

__global__ __launch_bounds__(256) void gat_csr(
    const float* __restrict__ xl, const float* __restrict__ xr,
    const float* __restrict__ att, const int* __restrict__ rowptr,
    const int* __restrict__ eidx, int n, float* __restrict__ agg)
{
    const int d    = (blockIdx.x * blockDim.x + threadIdx.x) >> 6;
    const int lane = threadIdx.x & 63;
    if (d >= n) return;

    const int h0 = lane >> 4;              // 0..3
    const int c4 = (lane & 15) << 2;       // 0..60
    const int o0 = h0 * 64 + c4;           // heads 0..3
    const int o1 = o0 + 256;               // heads 4..7

    const float4 r0 = *reinterpret_cast<const float4*>(&xr[(size_t)d * HD + o0]);
    const float4 r1 = *reinterpret_cast<const float4*>(&xr[(size_t)d * HD + o1]);
    const float4 a0 = *reinterpret_cast<const float4*>(&att[o0]);
    const float4 a1 = *reinterpret_cast<const float4*>(&att[o1]);

    float4 acc0 = make_float4(0.f, 0.f, 0.f, 0.f);
    float4 acc1 = make_float4(0.f, 0.f, 0.f, 0.f);
    float  den0 = 0.f, den1 = 0.f;

    const int start = rowptr[d], end = rowptr[d + 1];
    int s_next = (start < end) ? eidx[start] : 0;

    for (int e = start; e < end; ++e) {
        const int s = s_next;
        if (e + 1 < end) s_next = eidx[e + 1];   // prefetch next src id

        const float4 v0 = *reinterpret_cast<const float4*>(&xl[(size_t)s * HD + o0]);
        const float4 v1 = *reinterpret_cast<const float4*>(&xl[(size_t)s * HD + o1]);

        float p0 = lrdot4(v0, r0, a0);
        float p1 = lrdot4(v1, r1, a1);
        #pragma unroll
        for (int m = 1; m < 16; m <<= 1) {       // reduce within 16-lane group
            p0 += __shfl_xor(p0, m, 64);
            p1 += __shfl_xor(p1, m, 64);
        }
        p0 = __expf(p0);
        p1 = __expf(p1);
        den0 += p0;
        den1 += p1;

        acc0.x = fmaf(v0.x, p0, acc0.x); acc0.y = fmaf(v0.y, p0, acc0.y);
        acc0.z = fmaf(v0.z, p0, acc0.z); acc0.w = fmaf(v0.w, p0, acc0.w);
        acc1.x = fmaf(v1.x, p1, acc1.x); acc1.y = fmaf(v1.y, p1, acc1.y);
        acc1.z = fmaf(v1.z, p1, acc1.z); acc1.w = fmaf(v1.w, p1, acc1.w);
    }

    const float i0 = 1.f / den0, i1 = 1.f / den1;   // deg >= 1 (self-loop)
    *reinterpret_cast<float4*>(&agg[(size_t)d * HD + o0]) =
        make_float4(acc0.x * i0, acc0.y * i0, acc0.z * i0, acc0.w * i0);
    *reinterpret_cast<float4*>(&agg[(size_t)d * HD + o1]) =
        make_float4(acc1.x * i1, acc1.y * i1, acc1.z * i1, acc1.w * i1);
}

// ---------------------------------------------------------------------------
// h1 = elu(agg + b1)   (layer-1 epilogue; concat order == [h][c] memory order)
// ---------------------------------------------------------------------------
__global__ __launch_bounds__(256) void bias_elu(
    const float* __restrict__ agg, const float* __restrict__ b,
    float* __restrict__ out, int total)
{
    const int i = blockIdx.x * blockDim.x + threadIdx.x;
    if (i >= total) return;
    const float v = agg[i] + b[i & (HD - 1)];
    out[i] = v > 0.f ? v : expm1f(v);
}

// ---------------------------------------------------------------------------
// out[n,c] = mean_h(agg[n,h,c]) + b2[c]   (layer-2 epilogue)
// ---------------------------------------------------------------------------
__global__ __launch_bounds__(256) void mean_bias(
    const float* __restrict__ agg, const float* __restrict__ b2,
    float* __restrict__ out, int total)
{
    const int i = blockIdx.x * blockDim.x + threadIdx.x;
    if (i >= total) return;
    const int n = i >> 6, c = i & 63;
    const float* a = agg + (size_t)n * HD + c;
    float sum = 0.f;
    #pragma unroll
    for (int h = 0; h < HH; ++h) sum += a[h * 64];
    out[i] = sum * 0.125f + b2[c];
}

// ---------------------------------------------------------------------------
extern "C" void kernel_launch(void* const* d_in, const int* in_sizes, int n_in,
                              void* d_out, int out_size, void* d_ws, size_t ws_size,
                              hipStream_t stream)
{
    const float* x    = (const float*)d_in[0];
    const int*   ei   = (const int*)  d_in[1];
    const float* Wl1  = (const float*)d_in[2];
    const float* Wr1  = (const float*)d_in[3];
    const float* att1 = (const float*)d_in[4];
    const float* b1   = (const float*)d_in[5];
    const float* Wl2  = (const float*)d_in[6];
    const float* Wr2  = (const float*)d_in[7];
    const float* att2 = (const float*)d_in[8];
    const float* b2   = (const float*)d_in[9];

    const int N  = in_sizes[0] / DD;   // 20000
    const int E  = in_sizes[1] / 2;    // 320000
    const int ET = E + N;              // edges + self-loops

    const int* srcs = ei;
    const int* dsts = ei + E;

    // workspace layout: 4*N*HD floats (164 MB) + CSR ints (~2.6 MB)
    float* ws  = (float*)d_ws;
    float* xl  = ws;                        // N*HD
    float* xr  = xl  + (size_t)N * HD;      // N*HD
    float* agg = xr  + (size_t)N * HD;      // N*HD
    float* h1  = agg + (size_t)N * HD;      // N*HD
    int* rowptr = (int*)(h1 + (size_t)N * HD);   // N+1
    int* deg    = rowptr + (N + 1);              // N
    int* cursor = deg + N;                       // N
    int* eidx   = cursor + N;                    // ET

    const dim3 gblk(256);
    const dim3 g1((HD + 63) / 64, (N + 63) / 64);
    const int  eblk = (ET + 255) / 256;
    const int  nblk = (N + 3) / 4;   // one WAVE per node -> N*64 threads -> N/4 blocks
    const int  tot  = N * HD;

    // ---- CSR build (shared by both layers) ----
    hipMemsetAsync(deg, 0, (size_t)N * sizeof(int), stream);
    hist_deg   <<<eblk, gblk, 0, stream>>>(dsts, E, ET, deg);
    scan_rowptr<<<1,    gblk, 0, stream>>>(deg, rowptr, cursor, N);
    scatter_csr<<<eblk, gblk, 0, stream>>>(srcs, dsts, E, ET, cursor, eidx);

    // ---- layer 1: GATv2Conv(64 -> 64, heads=8, concat) + ELU ----
    sgemm64<<<g1, gblk, 0, stream>>>(x, Wl1, xl, N, HD, DD);
    sgemm64<<<g1, gblk, 0, stream>>>(x, Wr1, xr, N, HD, DD);
    gat_csr<<<nblk, gblk, 0, stream>>>(xl, xr, att1, rowptr, eidx, N, agg);
    bias_elu<<<(tot + 255) / 256, gblk, 0, stream>>>(agg, b1, h1, tot);

    // ---- layer 2: GATv2Conv(512 -> 64, heads=8, mean) ----
    sgemm64<<<g1, gblk, 0, stream>>>(h1, Wl2, xl, N, HD, HD);
    sgemm64<<<g1, gblk, 0, stream>>>(h1, Wr2, xr, N, HD, HD);
    gat_csr<<<nblk, gblk, 0, stream>>>(xl, xr, att2, rowptr, eidx, N, agg);
    mean_bias<<<(N * DD + 255) / 256, gblk, 0, stream>>>(agg, b2, (float*)d_out, N * DD);
}

// Round 7
// 609.074 us; speedup vs baseline: 3.0999x; 1.1362x over previous
//
#include <hip/hip_runtime.h>
#include <math.h>

#define DD 64      // per-head channels
#define HH 8       // heads
#define HD 512     // HH*DD
#define NC 1024    // combined xl|xr row width

// ---------------------------------------------------------------------------
// Dual-B fp32 GEMM: C[M, 0..511] = A@B0, C[M, 512..1023] = A@B1.
// A: M x K row-major. B0,B1: K x 512 row-major. C row stride NC=1024.
// 128x128 tile, 256 threads, 8x8 micro-tile (2x2 blocks of 4x4 at +64),
// XOR-swizzled LDS (chunk ^ row&7), bijective XCD grid swizzle.
// Requires K % 16 == 0, grid = 8 * ceil(M/128) (divisible by 8).
// ---------------------------------------------------------------------------
__global__ __launch_bounds__(256) void sgemm_dual(
    const float* __restrict__ A, const float* __restrict__ B0,
    const float* __restrict__ B1, float* __restrict__ C, int M, int K)
{
    __shared__ __align__(16) float As[16 * 128];
    __shared__ __align__(16) float Bs[16 * 128];

    // XCD-aware swizzle: each XCD gets a contiguous chunk of (mtile,ntile) space
    const int nwg = gridDim.x;                       // 8 * MT, divisible by 8
    const int wg  = (blockIdx.x & 7) * (nwg >> 3) + (blockIdx.x >> 3);
    const int ntile = wg & 7;
    const int mtile = wg >> 3;

    const int bm    = mtile * 128;
    const int bn128 = ntile * 128;                   // 0..896
    const float* __restrict__ B = (bn128 < 512) ? B0 : B1;
    const int bn = bn128 & 511;                      // col offset within B half

    const int tid = threadIdx.x;
    const int tx  = tid & 15;          // col group
    const int ty  = tid >> 4;          // row group (0..15)

    // A staging: rows ar, ar+64; cols ac..ac+3
    const int ar = tid >> 2;           // 0..63
    const int ac = (tid & 3) << 2;     // 0,4,8,12
    // B staging: rows br0, br0+8; 16B chunk bc
    const int br0 = tid >> 5;          // 0..7
    const int bc  = tid & 31;          // chunk index (col = bc*4)

    float acc[8][8] = {};

    for (int k0 = 0; k0 < K; k0 += 16) {
        // ---- stage A (transposed, swizzled): As[kk][m], chunk ^= kk&7 ----
        #pragma unroll
        for (int half = 0; half < 2; ++half) {
            const int m   = ar + half * 64;
            const int row = bm + m;
            float4 av = make_float4(0.f, 0.f, 0.f, 0.f);
            if (row < M)
                av = *reinterpret_cast<const float4*>(&A[(size_t)row * K + k0 + ac]);
            const float avv[4] = {av.x, av.y, av.z, av.w};
            #pragma unroll
            for (int j = 0; j < 4; ++j) {
                const int kk = ac + j;
                As[kk * 128 + ((((m >> 2) ^ (kk & 7)) << 2) | (m & 3))] = avv[j];
            }
        }
        // ---- stage B (swizzled): Bs[r][c], chunk ^= r&7 ----
        #pragma unroll
        for (int half = 0; half < 2; ++half) {
            const int r = br0 + half * 8;
            const float4 bv = *reinterpret_cast<const float4*>(
                &B[(size_t)(k0 + r) * 512 + bn + (bc << 2)]);
            *reinterpret_cast<float4*>(&Bs[r * 128 + ((bc ^ (r & 7)) << 2)]) = bv;
        }
        __syncthreads();

        #pragma unroll
        for (int k = 0; k < 16; ++k) {
            const int ss = k & 7;
            float a[8], b[8];
            *reinterpret_cast<float4*>(&a[0]) =
                *reinterpret_cast<const float4*>(&As[k * 128 + ((ty ^ ss) << 2)]);
            *reinterpret_cast<float4*>(&a[4]) =
                *reinterpret_cast<const float4*>(&As[k * 128 + (((ty + 16) ^ ss) << 2)]);
            *reinterpret_cast<float4*>(&b[0]) =
                *reinterpret_cast<const float4*>(&Bs[k * 128 + ((tx ^ ss) << 2)]);
            *reinterpret_cast<float4*>(&b[4]) =
                *reinterpret_cast<const float4*>(&Bs[k * 128 + (((tx + 16) ^ ss) << 2)]);
            #pragma unroll
            for (int i = 0; i < 8; ++i)
                #pragma unroll
                for (int j = 0; j < 8; ++j)
                    acc[i][j] = fmaf(a[i], b[j], acc[i][j]);
        }
        __syncthreads();
    }

    // ---- epilogue: rows {ty*4+i, 64+ty*4+i}, cols {tx*4+j, 64+tx*4+j} ----
    #pragma unroll
    for (int i = 0; i < 8; ++i) {
        const int row = bm + ((i < 4) ? (ty * 4 + i) : (64 + ty * 4 + (i - 4)));
        if (row >= M) continue;
        float* cp = &C[(size_t)row * NC + bn128 + (tx << 2)];
        *reinterpret_cast<float4*>(cp) =
            make_float4(acc[i][0], acc[i][1], acc[i][2], acc[i][3]);
        *reinterpret_cast<float4*>(cp + 64) =
            make_float4(acc[i][4], acc[i][5], acc[i][6], acc[i][7]);
    }
}

// ---------------------------------------------------------------------------
// CSR build (per launch; edge list identical for both layers).
// ---------------------------------------------------------------------------
__global__ __launch_bounds__(256) void hist_deg(const int* __restrict__ dsts,
                                                int E, int ET, int* __restrict__ deg)
{
    const int w = blockIdx.x * blockDim.x + threadIdx.x;
    if (w >= ET) return;
    const int d = (w < E) ? dsts[w] : (w - E);   // w >= E: virtual self-loop
    atomicAdd(&deg[d], 1);
}

__global__ __launch_bounds__(256) void scan_rowptr(const int* __restrict__ deg,
                                                   int* __restrict__ rowptr,
                                                   int* __restrict__ cursor, int n)
{
    __shared__ int sums[256];
    const int tid   = threadIdx.x;
    const int chunk = (n + 255) / 256;
    const int lo = min(tid * chunk, n), hi = min(lo + chunk, n);

    int s = 0;
    for (int i = lo; i < hi; ++i) s += deg[i];
    sums[tid] = s;
    __syncthreads();

    for (int off = 1; off < 256; off <<= 1) {
        const int t = (tid >= off) ? sums[tid - off] : 0;
        __syncthreads();
        sums[tid] += t;
        __syncthreads();
    }

    int run = sums[tid] - s;   // exclusive prefix of this chunk
    for (int i = lo; i < hi; ++i) {
        rowptr[i] = run;
        cursor[i] = run;
        run += deg[i];
    }
    if (tid == 255) rowptr[n] = run;   // == ET
}

__global__ __launch_bounds__(256) void scatter_csr(const int* __restrict__ srcs,
                                                   const int* __restrict__ dsts,
                                                   int E, int ET,
                                                   int* __restrict__ cursor,
                                                   int* __restrict__ eidx)
{
    const int w = blockIdx.x * blockDim.x + threadIdx.x;
    if (w >= ET) return;
    int s, d;
    if (w < E) { s = srcs[w]; d = dsts[w]; }
    else       { s = w - E;   d = s; }
    const int pos = atomicAdd(&cursor[d], 1);
    eidx[pos] = s;
}

// ---------------------------------------------------------------------------
// Fused GATv2 edge pipeline + epilogue. One wave per dst node, CSR gather.
// xlr[n][1024]: cols 0..511 = xl, 512..1023 = xr.
// lane covers channels c4..c4+3 of heads h0=lane>>4 and h0+4.
// MODE 0: out[d*512 + o] = elu(agg + bias[o])        (layer 1 -> h1)
// MODE 1: out[d*64 + c]  = mean_h(agg) + bias[c]     (layer 2 -> final)
// ---------------------------------------------------------------------------
__device__ __forceinline__ float lrdot4(const float4 v, const float4 r, const float4 a)
{
    float t, s = 0.f;
    t = v.x + r.x; t = t > 0.f ? t : 0.2f * t; s = fmaf(t, a.x, s);
    t = v.y + r.y; t = t > 0.f ? t : 0.2f * t; s = fmaf(t, a.y, s);
    t = v.z + r.z; t = t > 0.f ? t : 0.2f * t; s = fmaf(t, a.z, s);
    t = v.w + r.w; t = t > 0.f ? t : 0.2f * t; s = fmaf(t, a.w, s);
    return s;
}

template<int MODE>
__global__ __launch_bounds__(256) void gat_fused(
    const float* __restrict__ xlr, const float* __restrict__ att,
    const float* __restrict__ bias, const int* __restrict__ rowptr,
    const int* __restrict__ eidx, int n, float* __restrict__ out)
{
    const int d    = (blockIdx.x * blockDim.x + threadIdx.x) >> 6;
    const int lane = threadIdx.x & 63;
    if (d >= n) return;

    const int h0 = lane >> 4;              // 0..3
    const int c4 = (lane & 15) << 2;       // 0..60
    const int o0 = h0 * 64 + c4;           // heads 0..3 offset in [0,512)
    const int o1 = o0 + 256;               // heads 4..7

    const float* xrd = xlr + (size_t)d * NC + 512;
    const float4 r0 = *reinterpret_cast<const float4*>(&xrd[o0]);
    const float4 r1 = *reinterpret_cast<const float4*>(&xrd[o1]);
    const float4 a0 = *reinterpret_cast<const float4*>(&att[o0]);
    const float4 a1 = *reinterpret_cast<const float4*>(&att[o1]);

    float4 acc0 = make_float4(0.f, 0.f, 0.f, 0.f);
    float4 acc1 = make_float4(0.f, 0.f, 0.f, 0.f);
    float  den0 = 0.f, den1 = 0.f;

    const int start = rowptr[d], end = rowptr[d + 1];   // deg >= 1 (self-loop)
    const float* rp = xlr + (size_t)eidx[start] * NC;
    float4 v0 = *reinterpret_cast<const float4*>(&rp[o0]);
    float4 v1 = *reinterpret_cast<const float4*>(&rp[o0 + 256]);

    for (int e = start; e < end; ++e) {
        float4 n0 = v0, n1 = v1;
        if (e + 1 < end) {                              // wave-uniform branch
            const float* np = xlr + (size_t)eidx[e + 1] * NC;
            n0 = *reinterpret_cast<const float4*>(&np[o0]);
            n1 = *reinterpret_cast<const float4*>(&np[o0 + 256]);
        }

        float p0 = lrdot4(v0, r0, a0);
        float p1 = lrdot4(v1, r1, a1);
        #pragma unroll
        for (int m = 1; m < 16; m <<= 1) {              // reduce 16-lane group
            p0 += __shfl_xor(p0, m, 64);
            p1 += __shfl_xor(p1, m, 64);
        }
        p0 = __expf(p0);                                // logits O(1): no max shift
        p1 = __expf(p1);
        den0 += p0;
        den1 += p1;

        acc0.x = fmaf(v0.x, p0, acc0.x); acc0.y = fmaf(v0.y, p0, acc0.y);
        acc0.z = fmaf(v0.z, p0, acc0.z); acc0.w = fmaf(v0.w, p0, acc0.w);
        acc1.x = fmaf(v1.x, p1, acc1.x); acc1.y = fmaf(v1.y, p1, acc1.y);
        acc1.z = fmaf(v1.z, p1, acc1.z); acc1.w = fmaf(v1.w, p1, acc1.w);

        v0 = n0; v1 = n1;
    }

    const float i0 = 1.f / den0, i1 = 1.f / den1;

    if (MODE == 0) {
        // elu(agg + b1) -> h1[d][512]
        const float4 b0 = *reinterpret_cast<const float4*>(&bias[o0]);
        const float4 b1v = *reinterpret_cast<const float4*>(&bias[o1]);
        float4 u0 = make_float4(fmaf(acc0.x, i0, b0.x),  fmaf(acc0.y, i0, b0.y),
                                fmaf(acc0.z, i0, b0.z),  fmaf(acc0.w, i0, b0.w));
        float4 u1 = make_float4(fmaf(acc1.x, i1, b1v.x), fmaf(acc1.y, i1, b1v.y),
                                fmaf(acc1.z, i1, b1v.z), fmaf(acc1.w, i1, b1v.w));
        u0.x = u0.x > 0.f ? u0.x : expm1f(u0.x);
        u0.y = u0.y > 0.f ? u0.y : expm1f(u0.y);
        u0.z = u0.z > 0.f ? u0.z : expm1f(u0.z);
        u0.w = u0.w > 0.f ? u0.w : expm1f(u0.w);
        u1.x = u1.x > 0.f ? u1.x : expm1f(u1.x);
        u1.y = u1.y > 0.f ? u1.y : expm1f(u1.y);
        u1.z = u1.z > 0.f ? u1.z : expm1f(u1.z);
        u1.w = u1.w > 0.f ? u1.w : expm1f(u1.w);
        *reinterpret_cast<float4*>(&out[(size_t)d * HD + o0]) = u0;
        *reinterpret_cast<float4*>(&out[(size_t)d * HD + o1]) = u1;
    } else {
        // mean over 8 heads + b2 -> out[d][64]
        float4 t = make_float4(fmaf(acc0.x, i0, acc1.x * i1),
                               fmaf(acc0.y, i0, acc1.y * i1),
                               fmaf(acc0.z, i0, acc1.z * i1),
                               fmaf(acc0.w, i0, acc1.w * i1));
        #pragma unroll
        for (int m = 16; m <= 32; m <<= 1) {   // reduce across h0 groups
            t.x += __shfl_xor(t.x, m, 64);
            t.y += __shfl_xor(t.y, m, 64);
            t.z += __shfl_xor(t.z, m, 64);
            t.w += __shfl_xor(t.w, m, 64);
        }
        if (h0 == 0) {
            const float4 bv = *reinterpret_cast<const float4*>(&bias[c4]);
            *reinterpret_cast<float4*>(&out[(size_t)d * DD + c4]) =
                make_float4(fmaf(t.x, 0.125f, bv.x), fmaf(t.y, 0.125f, bv.y),
                            fmaf(t.z, 0.125f, bv.z), fmaf(t.w, 0.125f, bv.w));
        }
    }
}

// ---------------------------------------------------------------------------
extern "C" void kernel_launch(void* const* d_in, const int* in_sizes, int n_in,
                              void* d_out, int out_size, void* d_ws, size_t ws_size,
                              hipStream_t stream)
{
    const float* x    = (const float*)d_in[0];
    const int*   ei   = (const int*)  d_in[1];
    const float* Wl1  = (const float*)d_in[2];
    const float* Wr1  = (const float*)d_in[3];
    const float* att1 = (const float*)d_in[4];
    const float* b1   = (const float*)d_in[5];
    const float* Wl2  = (const float*)d_in[6];
    const float* Wr2  = (const float*)d_in[7];
    const float* att2 = (const float*)d_in[8];
    const float* b2   = (const float*)d_in[9];

    const int N  = in_sizes[0] / DD;   // 20000
    const int E  = in_sizes[1] / 2;    // 320000
    const int ET = E + N;              // edges + self-loops

    const int* srcs = ei;
    const int* dsts = ei + E;

    // workspace: xlr N*1024 + h1 N*512 floats + CSR ints (~125 MB total)
    float* ws  = (float*)d_ws;
    float* xlr = ws;                          // N*NC
    float* h1  = xlr + (size_t)N * NC;        // N*HD
    int* rowptr = (int*)(h1 + (size_t)N * HD);    // N+1
    int* deg    = rowptr + (N + 1);               // N
    int* cursor = deg + N;                        // N
    int* eidx   = cursor + N;                     // ET

    const dim3 gblk(256);
    const int  eblk = (ET + 255) / 256;
    const int  nblk = (N + 3) / 4;             // one wave per node
    const int  MT   = (N + 127) / 128;         // 157
    const int  gemm_grid = 8 * MT;             // 1256, divisible by 8

    // ---- CSR build (shared by both layers) ----
    hipMemsetAsync(deg, 0, (size_t)N * sizeof(int), stream);
    hist_deg   <<<eblk, gblk, 0, stream>>>(dsts, E, ET, deg);
    scan_rowptr<<<1,    gblk, 0, stream>>>(deg, rowptr, cursor, N);
    scatter_csr<<<eblk, gblk, 0, stream>>>(srcs, dsts, E, ET, cursor, eidx);

    // ---- layer 1: GATv2Conv(64 -> 64, heads=8, concat) + ELU ----
    sgemm_dual<<<gemm_grid, gblk, 0, stream>>>(x, Wl1, Wr1, xlr, N, DD);
    gat_fused<0><<<nblk, gblk, 0, stream>>>(xlr, att1, b1, rowptr, eidx, N, h1);

    // ---- layer 2: GATv2Conv(512 -> 64, heads=8, mean) ----
    sgemm_dual<<<gemm_grid, gblk, 0, stream>>>(h1, Wl2, Wr2, xlr, N, HD);
    gat_fused<1><<<nblk, gblk, 0, stream>>>(xlr, att2, b2, rowptr, eidx, N, (float*)d_out);
}

// Round 8
// 410.587 us; speedup vs baseline: 4.5985x; 1.4834x over previous
//
#include <hip/hip_runtime.h>
#include <math.h>

#define DD 64      // per-head channels
#define HH 8       // heads
#define HD 512     // HH*DD
#define NC 1024    // combined xl|xr row width

typedef __attribute__((ext_vector_type(8))) short bf16x8;
typedef __attribute__((ext_vector_type(4))) float f32x4;

// ---------------------------------------------------------------------------
// bf16 split helpers (round-to-nearest-even)
// ---------------------------------------------------------------------------
__device__ __forceinline__ ushort bf16_rne(float f) {
    uint u = __float_as_uint(f);
    u += 0x7fffu + ((u >> 16) & 1u);
    return (ushort)(u >> 16);
}
__device__ __forceinline__ float bf16_tof(ushort h) {
    return __uint_as_float(((uint)h) << 16);
}

// elementwise fp32 -> (hi, lo) bf16 pair
__global__ __launch_bounds__(256) void split_mat(const float* __restrict__ in,
                                                 ushort* __restrict__ hi,
                                                 ushort* __restrict__ lo, int total)
{
    const int i = blockIdx.x * 256 + threadIdx.x;
    if (i >= total) return;
    const float f = in[i];
    const ushort h = bf16_rne(f);
    hi[i] = h;
    lo[i] = bf16_rne(f - bf16_tof(h));
}

// W0,W1: [K][512] fp32 -> Bt: [1024][K] bf16 hi/lo (transposed, concatenated)
__global__ __launch_bounds__(256) void split_wT(const float* __restrict__ W0,
                                                const float* __restrict__ W1,
                                                ushort* __restrict__ hi,
                                                ushort* __restrict__ lo, int kshift)
{
    const int K = 1 << kshift;
    const int i = blockIdx.x * 256 + threadIdx.x;    // i = c*K + k
    if (i >= 1024 * K) return;
    const int c = i >> kshift, k = i & (K - 1);
    const float* W = (c < 512) ? W0 : W1;
    const float f = W[(size_t)k * 512 + (c & 511)];
    const ushort h = bf16_rne(f);
    hi[i] = h;
    lo[i] = bf16_rne(f - bf16_tof(h));
}

// ---------------------------------------------------------------------------
// bf16x3 split-precision MFMA GEMM.
// A (hi/lo): [M][K] bf16 row-major. Bt (hi/lo): [1024][K] bf16 (B transposed).
// C: [M][1024] fp32. C = A@B via Ah*Bh + Ah*Bl + Al*Bh (lo*lo dropped).
// 128x128 tile, 4 waves in 2x2 quadrants of 64x64, BK=64,
// mfma_f32_16x16x32_bf16, XOR-swizzled LDS (chunk ^ row&7): conflict-free.
// grid = 8 * ceil(M/128) (divisible by 8), XCD-aware swizzle. K % 64 == 0.
// ---------------------------------------------------------------------------
__global__ __launch_bounds__(256) void gemm_bf16x3(
    const ushort* __restrict__ Ah, const ushort* __restrict__ Al,
    const ushort* __restrict__ Bh, const ushort* __restrict__ Bl,
    float* __restrict__ C, int M, int K)
{
    __shared__ __align__(16) ushort lAh[128 * 64];
    __shared__ __align__(16) ushort lAl[128 * 64];
    __shared__ __align__(16) ushort lBh[128 * 64];
    __shared__ __align__(16) ushort lBl[128 * 64];

    const int nwg = gridDim.x;                        // 8*MT, divisible by 8
    const int wg  = (blockIdx.x & 7) * (nwg >> 3) + (blockIdx.x >> 3);
    const int ntile = wg & 7, mtile = wg >> 3;
    const int bm = mtile * 128, bn = ntile * 128;

    const int tid  = threadIdx.x;
    const int wid  = tid >> 6;            // 0..3
    const int lane = tid & 63;
    const int wr = wid >> 1, wc = wid & 1;   // 2x2 wave quadrants (64x64)
    const int l15 = lane & 15, g = lane >> 4;

    f32x4 acc[4][4] = {};

    for (int k0 = 0; k0 < K; k0 += 64) {
        __syncthreads();                   // previous iter's reads done
        // ---- stage 128x64 tiles of A(hi,lo) and Bt(hi,lo), swizzled ----
        #pragma unroll
        for (int j = 0; j < 4; ++j) {
            const int c    = j * 256 + tid;       // 1024 chunks of 8 ushorts
            const int row  = c >> 3, wcn = c & 7;
            const int ldsi = row * 64 + (((wcn ^ (row & 7))) << 3);
            const int arow = bm + row;
            ulonglong2 avh = {0, 0}, avl = {0, 0};
            if (arow < M) {
                avh = *(const ulonglong2*)(Ah + (size_t)arow * K + k0 + wcn * 8);
                avl = *(const ulonglong2*)(Al + (size_t)arow * K + k0 + wcn * 8);
            }
            *(ulonglong2*)(lAh + ldsi) = avh;
            *(ulonglong2*)(lAl + ldsi) = avl;
            const size_t bo = (size_t)(bn + row) * K + k0 + wcn * 8;
            *(ulonglong2*)(lBh + ldsi) = *(const ulonglong2*)(Bh + bo);
            *(ulonglong2*)(lBl + ldsi) = *(const ulonglong2*)(Bl + bo);
        }
        __syncthreads();

        #pragma unroll
        for (int kk = 0; kk < 2; ++kk) {
            bf16x8 ah[4], al[4], bh[4], bl[4];
            #pragma unroll
            for (int m = 0; m < 4; ++m) {
                const int row = wr * 64 + m * 16 + l15;
                const int sc  = (kk * 4 + g) ^ (row & 7);
                const int idx = row * 64 + (sc << 3);
                ah[m] = *(const bf16x8*)(lAh + idx);
                al[m] = *(const bf16x8*)(lAl + idx);
            }
            #pragma unroll
            for (int n = 0; n < 4; ++n) {
                const int row = wc * 64 + n * 16 + l15;
                const int sc  = (kk * 4 + g) ^ (row & 7);
                const int idx = row * 64 + (sc << 3);
                bh[n] = *(const bf16x8*)(lBh + idx);
                bl[n] = *(const bf16x8*)(lBl + idx);
            }
            #pragma unroll
            for (int m = 0; m < 4; ++m)
                #pragma unroll
                for (int n = 0; n < 4; ++n) {
                    acc[m][n] = __builtin_amdgcn_mfma_f32_16x16x32_bf16(
                                    ah[m], bh[n], acc[m][n], 0, 0, 0);
                    acc[m][n] = __builtin_amdgcn_mfma_f32_16x16x32_bf16(
                                    ah[m], bl[n], acc[m][n], 0, 0, 0);
                    acc[m][n] = __builtin_amdgcn_mfma_f32_16x16x32_bf16(
                                    al[m], bh[n], acc[m][n], 0, 0, 0);
                }
        }
    }

    // ---- C write: D frag (row=(g*4+i), col=l15) at (wr*64+m*16, wc*64+n*16)
    #pragma unroll
    for (int m = 0; m < 4; ++m) {
        #pragma unroll
        for (int i = 0; i < 4; ++i) {
            const int row = bm + wr * 64 + m * 16 + g * 4 + i;
            if (row >= M) continue;
            float* cp = C + (size_t)row * NC + bn + wc * 64 + l15;
            #pragma unroll
            for (int n = 0; n < 4; ++n)
                cp[n * 16] = acc[m][n][i];
        }
    }
}

// ---------------------------------------------------------------------------
// CSR build (per launch; edge list identical for both layers).
// ---------------------------------------------------------------------------
__global__ __launch_bounds__(256) void hist_deg(const int* __restrict__ dsts,
                                                int E, int ET, int* __restrict__ deg)
{
    const int w = blockIdx.x * blockDim.x + threadIdx.x;
    if (w >= ET) return;
    const int d = (w < E) ? dsts[w] : (w - E);   // w >= E: virtual self-loop
    atomicAdd(&deg[d], 1);
}

__global__ __launch_bounds__(256) void scan_rowptr(const int* __restrict__ deg,
                                                   int* __restrict__ rowptr,
                                                   int* __restrict__ cursor, int n)
{
    __shared__ int sums[256];
    const int tid   = threadIdx.x;
    const int chunk = (n + 255) / 256;
    const int lo = min(tid * chunk, n), hi = min(lo + chunk, n);

    int s = 0;
    for (int i = lo; i < hi; ++i) s += deg[i];
    sums[tid] = s;
    __syncthreads();

    for (int off = 1; off < 256; off <<= 1) {
        const int t = (tid >= off) ? sums[tid - off] : 0;
        __syncthreads();
        sums[tid] += t;
        __syncthreads();
    }

    int run = sums[tid] - s;   // exclusive prefix of this chunk
    for (int i = lo; i < hi; ++i) {
        rowptr[i] = run;
        cursor[i] = run;
        run += deg[i];
    }
    if (tid == 255) rowptr[n] = run;   // == ET
}

__global__ __launch_bounds__(256) void scatter_csr(const int* __restrict__ srcs,
                                                   const int* __restrict__ dsts,
                                                   int E, int ET,
                                                   int* __restrict__ cursor,
                                                   int* __restrict__ eidx)
{
    const int w = blockIdx.x * blockDim.x + threadIdx.x;
    if (w >= ET) return;
    int s, d;
    if (w < E) { s = srcs[w]; d = dsts[w]; }
    else       { s = w - E;   d = s; }
    const int pos = atomicAdd(&cursor[d], 1);
    eidx[pos] = s;
}

// ---------------------------------------------------------------------------
// Fused GATv2 edge pipeline + epilogue. One wave per dst node, CSR gather.
// xlr[n][1024]: cols 0..511 = xl, 512..1023 = xr.
// MODE 0: h = elu(agg + bias); write bf16 hi/lo pair (feeds layer-2 GEMM)
// MODE 1: out[d*64 + c] = mean_h(agg) + bias[c]  (final fp32 output)
// ---------------------------------------------------------------------------
__device__ __forceinline__ float lrdot4(const float4 v, const float4 r, const float4 a)
{
    float t, s = 0.f;
    t = v.x + r.x; t = t > 0.f ? t : 0.2f * t; s = fmaf(t, a.x, s);
    t = v.y + r.y; t = t > 0.f ? t : 0.2f * t; s = fmaf(t, a.y, s);
    t = v.z + r.z; t = t > 0.f ? t : 0.2f * t; s = fmaf(t, a.z, s);
    t = v.w + r.w; t = t > 0.f ? t : 0.2f * t; s = fmaf(t, a.w, s);
    return s;
}

template<int MODE>
__global__ __launch_bounds__(256) void gat_fused(
    const float* __restrict__ xlr, const float* __restrict__ att,
    const float* __restrict__ bias, const int* __restrict__ rowptr,
    const int* __restrict__ eidx, int n, float* __restrict__ out,
    ushort* __restrict__ oh, ushort* __restrict__ ol)
{
    const int d    = (blockIdx.x * blockDim.x + threadIdx.x) >> 6;
    const int lane = threadIdx.x & 63;
    if (d >= n) return;

    const int h0 = lane >> 4;              // 0..3
    const int c4 = (lane & 15) << 2;       // 0..60
    const int o0 = h0 * 64 + c4;           // heads 0..3 offset in [0,512)
    const int o1 = o0 + 256;               // heads 4..7

    const float* xrd = xlr + (size_t)d * NC + 512;
    const float4 r0 = *reinterpret_cast<const float4*>(&xrd[o0]);
    const float4 r1 = *reinterpret_cast<const float4*>(&xrd[o1]);
    const float4 a0 = *reinterpret_cast<const float4*>(&att[o0]);
    const float4 a1 = *reinterpret_cast<const float4*>(&att[o1]);

    float4 acc0 = make_float4(0.f, 0.f, 0.f, 0.f);
    float4 acc1 = make_float4(0.f, 0.f, 0.f, 0.f);
    float  den0 = 0.f, den1 = 0.f;

    const int start = rowptr[d], end = rowptr[d + 1];   // deg >= 1 (self-loop)
    const float* rp = xlr + (size_t)eidx[start] * NC;
    float4 v0 = *reinterpret_cast<const float4*>(&rp[o0]);
    float4 v1 = *reinterpret_cast<const float4*>(&rp[o0 + 256]);

    for (int e = start; e < end; ++e) {
        float4 n0 = v0, n1 = v1;
        if (e + 1 < end) {                              // wave-uniform branch
            const float* np = xlr + (size_t)eidx[e + 1] * NC;
            n0 = *reinterpret_cast<const float4*>(&np[o0]);
            n1 = *reinterpret_cast<const float4*>(&np[o0 + 256]);
        }

        float p0 = lrdot4(v0, r0, a0);
        float p1 = lrdot4(v1, r1, a1);
        #pragma unroll
        for (int m = 1; m < 16; m <<= 1) {              // reduce 16-lane group
            p0 += __shfl_xor(p0, m, 64);
            p1 += __shfl_xor(p1, m, 64);
        }
        p0 = __expf(p0);                                // logits O(1): no max shift
        p1 = __expf(p1);
        den0 += p0;
        den1 += p1;

        acc0.x = fmaf(v0.x, p0, acc0.x); acc0.y = fmaf(v0.y, p0, acc0.y);
        acc0.z = fmaf(v0.z, p0, acc0.z); acc0.w = fmaf(v0.w, p0, acc0.w);
        acc1.x = fmaf(v1.x, p1, acc1.x); acc1.y = fmaf(v1.y, p1, acc1.y);
        acc1.z = fmaf(v1.z, p1, acc1.z); acc1.w = fmaf(v1.w, p1, acc1.w);

        v0 = n0; v1 = n1;
    }

    const float i0 = 1.f / den0, i1 = 1.f / den1;

    if (MODE == 0) {
        // elu(agg + b1), emitted as bf16 hi/lo split for the next GEMM
        const float4 b0  = *reinterpret_cast<const float4*>(&bias[o0]);
        const float4 b1v = *reinterpret_cast<const float4*>(&bias[o1]);
        float u[8];
        u[0] = fmaf(acc0.x, i0, b0.x);  u[1] = fmaf(acc0.y, i0, b0.y);
        u[2] = fmaf(acc0.z, i0, b0.z);  u[3] = fmaf(acc0.w, i0, b0.w);
        u[4] = fmaf(acc1.x, i1, b1v.x); u[5] = fmaf(acc1.y, i1, b1v.y);
        u[6] = fmaf(acc1.z, i1, b1v.z); u[7] = fmaf(acc1.w, i1, b1v.w);
        ushort hx[8], lx[8];
        #pragma unroll
        for (int j = 0; j < 8; ++j) {
            const float v = u[j] > 0.f ? u[j] : expm1f(u[j]);
            hx[j] = bf16_rne(v);
            lx[j] = bf16_rne(v - bf16_tof(hx[j]));
        }
        *reinterpret_cast<ushort4*>(&oh[(size_t)d * HD + o0]) =
            make_ushort4(hx[0], hx[1], hx[2], hx[3]);
        *reinterpret_cast<ushort4*>(&oh[(size_t)d * HD + o1]) =
            make_ushort4(hx[4], hx[5], hx[6], hx[7]);
        *reinterpret_cast<ushort4*>(&ol[(size_t)d * HD + o0]) =
            make_ushort4(lx[0], lx[1], lx[2], lx[3]);
        *reinterpret_cast<ushort4*>(&ol[(size_t)d * HD + o1]) =
            make_ushort4(lx[4], lx[5], lx[6], lx[7]);
    } else {
        // mean over 8 heads + b2 -> out[d][64]
        float4 t = make_float4(fmaf(acc0.x, i0, acc1.x * i1),
                               fmaf(acc0.y, i0, acc1.y * i1),
                               fmaf(acc0.z, i0, acc1.z * i1),
                               fmaf(acc0.w, i0, acc1.w * i1));
        #pragma unroll
        for (int m = 16; m <= 32; m <<= 1) {   // reduce across h0 groups
            t.x += __shfl_xor(t.x, m, 64);
            t.y += __shfl_xor(t.y, m, 64);
            t.z += __shfl_xor(t.z, m, 64);
            t.w += __shfl_xor(t.w, m, 64);
        }
        if (h0 == 0) {
            const float4 bv = *reinterpret_cast<const float4*>(&bias[c4]);
            *reinterpret_cast<float4*>(&out[(size_t)d * DD + c4]) =
                make_float4(fmaf(t.x, 0.125f, bv.x), fmaf(t.y, 0.125f, bv.y),
                            fmaf(t.z, 0.125f, bv.z), fmaf(t.w, 0.125f, bv.w));
        }
    }
}

// ---------------------------------------------------------------------------
extern "C" void kernel_launch(void* const* d_in, const int* in_sizes, int n_in,
                              void* d_out, int out_size, void* d_ws, size_t ws_size,
                              hipStream_t stream)
{
    const float* x    = (const float*)d_in[0];
    const int*   ei   = (const int*)  d_in[1];
    const float* Wl1  = (const float*)d_in[2];
    const float* Wr1  = (const float*)d_in[3];
    const float* att1 = (const float*)d_in[4];
    const float* b1   = (const float*)d_in[5];
    const float* Wl2  = (const float*)d_in[6];
    const float* Wr2  = (const float*)d_in[7];
    const float* att2 = (const float*)d_in[8];
    const float* b2   = (const float*)d_in[9];

    const int N  = in_sizes[0] / DD;   // 20000
    const int E  = in_sizes[1] / 2;    // 320000
    const int ET = E + N;              // edges + self-loops

    const int* srcs = ei;
    const int* dsts = ei + E;

    // ---- workspace layout ----
    float*  xlr   = (float*)d_ws;                       // N*1024 f32 (82 MB)
    ushort* xs_h  = (ushort*)(xlr + (size_t)N * NC);    // N*64
    ushort* xs_l  = xs_h  + (size_t)N * DD;             // N*64
    ushort* h1_h  = xs_l  + (size_t)N * DD;             // N*512
    ushort* h1_l  = h1_h  + (size_t)N * HD;             // N*512
    ushort* bt1_h = h1_l  + (size_t)N * HD;             // 1024*64
    ushort* bt1_l = bt1_h + 1024 * DD;                  // 1024*64
    ushort* bt2_h = bt1_l + 1024 * DD;                  // 1024*512
    ushort* bt2_l = bt2_h + 1024 * HD;                  // 1024*512
    int* rowptr = (int*)(bt2_l + 1024 * HD);            // N+1
    int* deg    = rowptr + (N + 1);                     // N
    int* cursor = deg + N;                              // N
    int* eidx   = cursor + N;                           // ET

    const dim3 gblk(256);
    const int  eblk = (ET + 255) / 256;
    const int  nblk = (N + 3) / 4;             // one wave per node
    const int  MT   = (N + 127) / 128;         // 157
    const int  gemm_grid = 8 * MT;             // 1256, divisible by 8

    // ---- CSR build (shared by both layers) ----
    hipMemsetAsync(deg, 0, (size_t)N * sizeof(int), stream);
    hist_deg   <<<eblk, gblk, 0, stream>>>(dsts, E, ET, deg);
    scan_rowptr<<<1,    gblk, 0, stream>>>(deg, rowptr, cursor, N);
    scatter_csr<<<eblk, gblk, 0, stream>>>(srcs, dsts, E, ET, cursor, eidx);

    // ---- split inputs / weights to bf16 hi/lo ----
    split_mat<<<(N * DD + 255) / 256, gblk, 0, stream>>>(x, xs_h, xs_l, N * DD);
    split_wT <<<(1024 * DD + 255) / 256, gblk, 0, stream>>>(Wl1, Wr1, bt1_h, bt1_l, 6);
    split_wT <<<(1024 * HD + 255) / 256, gblk, 0, stream>>>(Wl2, Wr2, bt2_h, bt2_l, 9);

    // ---- layer 1: GATv2Conv(64 -> 64, heads=8, concat) + ELU ----
    gemm_bf16x3<<<gemm_grid, gblk, 0, stream>>>(xs_h, xs_l, bt1_h, bt1_l, xlr, N, DD);
    gat_fused<0><<<nblk, gblk, 0, stream>>>(xlr, att1, b1, rowptr, eidx, N,
                                            nullptr, h1_h, h1_l);

    // ---- layer 2: GATv2Conv(512 -> 64, heads=8, mean) ----
    gemm_bf16x3<<<gemm_grid, gblk, 0, stream>>>(h1_h, h1_l, bt2_h, bt2_l, xlr, N, HD);
    gat_fused<1><<<nblk, gblk, 0, stream>>>(xlr, att2, b2, rowptr, eidx, N,
                                            (float*)d_out, nullptr, nullptr);
}